// Round 15
// baseline (97.088 us; speedup 1.0000x reference)
//
#include <hip/hip_runtime.h>
#include <math.h>

#define TT 128
#define IN_CH 32
#define NPATH 256
#define SIGCH 7380
#define K1 29520
#define N1 512
#define N2 256
#define BKG 8

// ---------------- Kernel 1: conv + time-augment + depth-4 signature ----------------
// 512-thread block per path, 2 groups of 243 threads, Chen 2-way time-split.
// Scan inner loop: per 4-step group load A4[9] (broadcast b128) + e/f (6 b128)
// into registers, then 4 steps of pure VALU with compile-time component access
// -> NO v_readlane in the scan (prior version: 9/step = 576/thread).
__global__ __launch_bounds__(512, 2) void sig_kernel(const float* __restrict__ x,
        const float* __restrict__ cw, const float* __restrict__ cb,
        float* __restrict__ sig /*[256][7380]*/) {
    __shared__ float incT[9][132];
    __shared__ __align__(16) float sb1[12];
    __shared__ __align__(16) float sb2[9][12];
    __shared__ __align__(16) float sb3[81][12];
    __shared__ __align__(16) float sb4[729][12];
    const int p = blockIdx.x;
    const int b = p >> 2, oc = p & 3;
    const int tid = threadIdx.x;

    const float4 wv = *(const float4*)(cw + oc * 4);
    const float bias = cb[oc];
    const float* xb = x + (long)b * TT * IN_CH;

    for (int it = tid; it < TT * 8; it += 512) {
        const int t = it >> 3, ch = it & 7;
        const float4 xa = *(const float4*)(xb + t * IN_CH + ch * 4);
        float v = xa.x * wv.x + xa.y * wv.y + xa.z * wv.z + xa.w * wv.w + bias;
        if (t > 0) {
            const float4 xm = *(const float4*)(xb + (t - 1) * IN_CH + ch * 4);
            v -= xm.x * wv.x + xm.y * wv.y + xm.z * wv.z + xm.w * wv.w + bias;
        }
        incT[1 + ch][t] = v;
    }
    if (tid < TT) incT[0][tid] = tid ? (1.f / 127.f) : 0.f;
    __syncthreads();

    const int g = tid >> 8;
    const int gtid = tid & 255;
    const bool act = gtid < 243;
    const int base3 = 3 * gtid;
    const int i1 = base3 / 81;
    const int i2 = (base3 / 9) % 9;
    const int i30 = base3 % 9;

    float S4[3][9] = {};
    float s3[3] = {0.f, 0.f, 0.f};
    float s2 = 0.f, s1 = 0.f;

#define LD(R, T4) (*(const float4*)&incT[(R)][(T4)])
#define STEP4(CMP) do { \
    const float E1 = e1v.CMP, E2 = e2v.CMP; \
    const float F0 = f0v.CMP, F1 = f1v.CMP, F2 = f2v.CMP; \
    const float t12 = E1 * E2; \
    const float s1d2 = s1 * E2; \
    const float Ak = t12 * (1.f / 24.f) + s1d2 * (1.f / 6.f) + s2 * 0.5f; \
    const float Bk = t12 * (1.f / 6.f) + s1d2 * 0.5f + s2; \
    const float K0 = F0 * Ak + s3[0]; \
    const float K1v = F1 * Ak + s3[1]; \
    const float K2v = F2 * Ak + s3[2]; \
    _Pragma("unroll") \
    for (int c = 0; c < 9; ++c) { \
        const float Ac = A4[c].CMP; \
        S4[0][c] += K0 * Ac; S4[1][c] += K1v * Ac; S4[2][c] += K2v * Ac; \
    } \
    s3[0] += Bk * F0; s3[1] += Bk * F1; s3[2] += Bk * F2; \
    s2 += E2 * (0.5f * E1 + s1); \
    s1 += E1; \
} while (0)

    if (act) {
        const int t0g = g * 64;
        for (int gg = 0; gg < 16; ++gg) {
            const int t4 = t0g + gg * 4;
            float4 A4[9];
#pragma unroll
            for (int c = 0; c < 9; ++c) A4[c] = LD(c, t4);
            const float4 e1v = LD(i1, t4), e2v = LD(i2, t4);
            const float4 f0v = LD(i30, t4), f1v = LD(i30 + 1, t4), f2v = LD(i30 + 2, t4);
            STEP4(x); STEP4(y); STEP4(z); STEP4(w);
        }
    }
#undef STEP4
#undef LD

    if (act && g == 1) {
        if (i2 == 0 && i30 == 0) sb1[i1] = s1;
        if (i30 == 0) sb2[i1][i2] = s2;
#pragma unroll
        for (int q = 0; q < 3; ++q) sb3[i1 * 9 + i2][i30 + q] = s3[q];
#pragma unroll
        for (int q = 0; q < 3; ++q)
#pragma unroll
            for (int c = 0; c < 9; ++c) sb4[base3 + q][c] = S4[q][c];
    }
    __syncthreads();

    if (act && g == 0) {
        float S1B[9];
#pragma unroll
        for (int c = 0; c < 9; ++c) S1B[c] = sb1[c];
#pragma unroll
        for (int q = 0; q < 3; ++q) {
            const float* r2 = sb2[i30 + q];
            const float* r3 = sb3[i2 * 9 + i30 + q];
            const float* r4 = sb4[base3 + q];
#pragma unroll
            for (int c = 0; c < 9; ++c)
                S4[q][c] += s3[q] * S1B[c] + s2 * r2[c] + s1 * r3[c] + r4[c];
        }
#pragma unroll
        for (int q = 0; q < 3; ++q)
            s3[q] += s2 * S1B[i30 + q] + s1 * sb2[i2][i30 + q] + sb3[i1 * 9 + i2][i30 + q];
        s2 += s1 * S1B[i2] + sb2[i1][i2];
        s1 += S1B[i1];

        float* sp = sig + (long)p * SIGCH;
        if (i2 == 0 && i30 == 0) sp[i1] = s1;
        if (i30 == 0) sp[9 + base3 / 9] = s2;
        sp[90 + base3 + 0] = s3[0];
        sp[90 + base3 + 1] = s3[1];
        sp[90 + base3 + 2] = s3[2];
#pragma unroll
        for (int q = 0; q < 3; q++)
#pragma unroll
            for (int l = 0; l < 9; l++)
                sp[819 + (base3 + q) * 9 + l] = S4[q][l];
    }
}

// ---------------- Kernel 2: GEMM1 partials (readlane-z, minimal LDS) ----------------
// 512 thr / 8 waves, full 64x512 tile, grid = pure k-split (246 blocks).
// Wave = 8 rows x 512 cols. z: ONE global_load_dword per lane per BK=8 tile
// (lane=(k,r)); hot loop gets the wave-uniform z scalar via v_readlane -> SGPR
// -> FMA with SGPR src. NO z in LDS, NO s_load. w tile [8][512] LDS dbuf with
// lane-CONTIGUOUS staging writes (canonical conflict-free b128). Per k/wave:
// 2 ds_read_b128 + 8 readlane + 64 FMA -> VALU-bound.
__global__ __launch_bounds__(512) void gemm1_kernel(const float* __restrict__ zsig,
        const float* __restrict__ w0, float* __restrict__ part, int KCH) {
    __shared__ float wt[2][BKG][512];
    const int kc = blockIdx.x;
    const int k0 = kc * KCH;
    const int tid = threadIdx.x;
    const int lane = tid & 63;
    const int wvid = __builtin_amdgcn_readfirstlane(tid >> 6);  // 0..7
    const int r0 = wvid * 8;
    const int c4a = lane * 4, c4b = 256 + lane * 4;
    const int sr = tid >> 7;             // 0..3 (also stages row sr+4)
    const int sc = (tid & 127) * 4;      // lane-contiguous columns

    const long zoff = (long)(r0 + (lane & 7)) * K1 + (lane >> 3);

#define RLF(V, L) __int_as_float(__builtin_amdgcn_readlane(__float_as_int(V), (L)))

    float4 wA, wB, wA2, wB2;
    float zv, zv2;
    {
        const float* wp = w0 + (long)(k0 + sr) * N1 + sc;
        wA = *(const float4*)wp;
        wB = *(const float4*)(wp + 4 * N1);
        zv = zsig[zoff + k0];
    }
    *(float4*)&wt[0][sr][sc] = wA;
    *(float4*)&wt[0][sr + 4][sc] = wB;
    __syncthreads();

    float acc[8][8] = {};
    const int NT = KCH / BKG;
    int cur = 0;

    for (int t = 0; t < NT; ++t) {
        if (t + 1 < NT) {
            const int kn = k0 + (t + 1) * BKG;
            zv2 = zsig[zoff + kn];
            const float* wp = w0 + (long)(kn + sr) * N1 + sc;
            wA2 = *(const float4*)wp;
            wB2 = *(const float4*)(wp + 4 * N1);
        }
#pragma unroll
        for (int k = 0; k < BKG; ++k) {
            const float4 wfa = *(const float4*)&wt[cur][k][c4a];
            const float4 wfb = *(const float4*)&wt[cur][k][c4b];
#define ROW(R) do { \
            const float sz = RLF(zv, k * 8 + (R)); \
            acc[R][0] += sz * wfa.x; acc[R][1] += sz * wfa.y; \
            acc[R][2] += sz * wfa.z; acc[R][3] += sz * wfa.w; \
            acc[R][4] += sz * wfb.x; acc[R][5] += sz * wfb.y; \
            acc[R][6] += sz * wfb.z; acc[R][7] += sz * wfb.w; } while (0)
            ROW(0); ROW(1); ROW(2); ROW(3); ROW(4); ROW(5); ROW(6); ROW(7);
#undef ROW
        }
        if (t + 1 < NT) {
            *(float4*)&wt[cur ^ 1][sr][sc] = wA2;
            *(float4*)&wt[cur ^ 1][sr + 4][sc] = wB2;
        }
        __syncthreads();
        cur ^= 1;
        zv = zv2;
    }
#undef RLF

    float* pp = part + ((long)kc * 64 + r0) * N1;
#pragma unroll
    for (int r = 0; r < 8; r++) {
        *(float4*)(pp + (long)r * N1 + c4a) =
            make_float4(acc[r][0], acc[r][1], acc[r][2], acc[r][3]);
        *(float4*)(pp + (long)r * N1 + c4b) =
            make_float4(acc[r][4], acc[r][5], acc[r][6], acc[r][7]);
    }
}

// ---------------- Kernel 3: reduce partials + bias + sigmoid ----------------
__global__ __launch_bounds__(256) void red1_kernel(const float* __restrict__ part,
        const float* __restrict__ b0v, float* __restrict__ z1, int ksplit) {
    __shared__ float4 red[256];
    const int tid = threadIdx.x;
    const int g = tid & 31, s = tid >> 5;
    const int gg = blockIdx.x * 32 + g;
    const int per = (ksplit + 7) >> 3;
    const int ks = s * per, ke = min(ksplit, ks + per);
    float4 a = make_float4(0.f, 0.f, 0.f, 0.f);
    for (int kc = ks; kc < ke; kc++) {
        float4 pv = *(const float4*)(part + ((long)kc * 8192 + gg) * 4);
        a.x += pv.x; a.y += pv.y; a.z += pv.z; a.w += pv.w;
    }
    red[tid] = a;
    __syncthreads();
    if (tid < 128) { float4 o = red[tid + 128]; red[tid].x += o.x; red[tid].y += o.y; red[tid].z += o.z; red[tid].w += o.w; }
    __syncthreads();
    if (tid < 64) { float4 o = red[tid + 64]; red[tid].x += o.x; red[tid].y += o.y; red[tid].z += o.z; red[tid].w += o.w; }
    __syncthreads();
    if (tid < 32) {
        float4 sum = red[tid];
        float4 o = red[tid + 32];
        sum.x += o.x; sum.y += o.y; sum.z += o.z; sum.w += o.w;
        const float4 bv = *(const float4*)(b0v + (gg & 127) * 4);
        float4 r;
        r.x = 1.f / (1.f + expf(-(sum.x + bv.x)));
        r.y = 1.f / (1.f + expf(-(sum.y + bv.y)));
        r.z = 1.f / (1.f + expf(-(sum.z + bv.z)));
        r.w = 1.f / (1.f + expf(-(sum.w + bv.w)));
        *(float4*)(z1 + gg * 4) = r;
    }
}

// ---------------- Kernel 4: fused GEMM2+sigmoid+GEMM3+log_softmax ----------------
__global__ __launch_bounds__(256) void tail_kernel(const float* __restrict__ z1,
        const float* __restrict__ w1, const float* __restrict__ b1v,
        const float* __restrict__ w2, const float* __restrict__ b2v,
        float* __restrict__ out) {
    __shared__ float z2row[N2];
    __shared__ float red[160];
    __shared__ float logits[10];
    const int m = blockIdx.x;
    const int tid = threadIdx.x;
    const float* zr = z1 + m * N1;
    float acc = b1v[tid];
#pragma unroll 8
    for (int k = 0; k < N1; k++) acc += zr[k] * w1[(long)k * N2 + tid];
    z2row[tid] = 1.f / (1.f + expf(-acc));
    __syncthreads();
    if (tid < 160) {
        const int j = tid >> 4, s = tid & 15;
        float p = 0.f;
#pragma unroll
        for (int kk = 0; kk < 16; kk++) {
            const int k = s * 16 + kk;
            p += z2row[k] * w2[k * 10 + j];
        }
        red[tid] = p;
    }
    __syncthreads();
    if (tid < 10) {
        float lg = b2v[tid];
#pragma unroll
        for (int s = 0; s < 16; s++) lg += red[tid * 16 + s];
        logits[tid] = lg;
    }
    __syncthreads();
    if (tid == 0) {
        float mx = logits[0];
        for (int j = 1; j < 10; j++) mx = fmaxf(mx, logits[j]);
        float sum = 0.f;
        for (int j = 0; j < 10; j++) sum += expf(logits[j] - mx);
        const float lse = mx + logf(sum);
        for (int j = 0; j < 10; j++) out[m * 10 + j] = logits[j] - lse;
    }
}

extern "C" void kernel_launch(void* const* d_in, const int* in_sizes, int n_in,
                              void* d_out, int out_size, void* d_ws, size_t ws_size,
                              hipStream_t stream) {
    const float* x  = (const float*)d_in[0];
    const float* cw = (const float*)d_in[1];
    const float* cb = (const float*)d_in[2];
    const float* w0 = (const float*)d_in[3];
    const float* b0 = (const float*)d_in[4];
    const float* w1 = (const float*)d_in[5];
    const float* b1 = (const float*)d_in[6];
    const float* w2 = (const float*)d_in[7];
    const float* b2 = (const float*)d_in[8];

    // tiered K-split by workspace: 29520 = ksplit * KCH, KCH % 8 == 0
    const size_t fixed = (size_t)NPATH * SIGCH + 64 * N1 + 64 * N2;
    int ksplit = 82, kch = 360;
    if (ws_size >= (fixed + (size_t)246 * 64 * N1) * 4)      { ksplit = 246; kch = 120; }
    else if (ws_size >= (fixed + (size_t)123 * 64 * N1) * 4) { ksplit = 123; kch = 240; }

    float* ws   = (float*)d_ws;
    float* sigb = ws;                                // 256 x 7380 row-major
    float* part = sigb + (long)NPATH * SIGCH;        // ksplit*64*512
    float* z1   = part + (long)ksplit * 64 * N1;     // 64*512
    float* out  = (float*)d_out;

    sig_kernel<<<NPATH, 512, 0, stream>>>(x, cw, cb, sigb);
    gemm1_kernel<<<ksplit, 512, 0, stream>>>(sigb, w0, part, kch);
    red1_kernel<<<256, 256, 0, stream>>>(part, b0, z1, ksplit);
    tail_kernel<<<64, 256, 0, stream>>>(z1, w1, b1, w2, b2, out);
}